// Round 8
// baseline (419.184 us; speedup 1.0000x reference)
//
#include <hip/hip_runtime.h>
#include <stdint.h>

#define BS 16
#define NP 25200
#define NC 80
#define DIM 85
#define KN 2048
#define CAP 4096
#define BINS 512
#define MAXD 300
#define NBLK 394   // ceil(25200/64)
#define GBLK 25    // gather blocks per batch (1024 threads each)

// async global->LDS, 16B per lane (lds dest = wave-uniform base + lane*16)
#define GLOAD_LDS16(g, l) __builtin_amdgcn_global_load_lds( \
    (__attribute__((address_space(1))) void*)(g), \
    (__attribute__((address_space(3))) void*)(l), 16, 0, 0)

// ---------------------------------------------------------------- score
// Staging via global_load_lds dwordx4 (round-7: 91 -> <80 µs).
__global__ __launch_bounds__(256) void score_kernel(const float* __restrict__ preds,
        float* __restrict__ score, int* __restrict__ clsout, int* __restrict__ hist) {
    int b = blockIdx.x / NBLK;
    int blk = blockIdx.x % NBLK;
    int i0 = blk * 64;
    int nb = min(64, NP - i0);
    __shared__ float4 s4[64 * DIM / 4];   // 21760 B
    const float4* p4 = (const float4*)(preds + ((size_t)b * NP + i0) * DIM);
    int tot4 = (nb * DIM) >> 2;           // 1360 (full) or 1020 (tail), exact
    int wave = threadIdx.x >> 6, lane = threadIdx.x & 63;
    for (int it = wave; it * 64 < tot4; it += 4) {
        int idx = it * 64 + lane;
        if (idx < tot4) GLOAD_LDS16(p4 + idx, s4 + it * 64);
    }
    __syncthreads();   // compiler drains vmcnt before s_barrier
    const float* s = (const float*)s4;
    int box = threadIdx.x >> 2, sub = threadIdx.x & 3;
    if (box < nb) {
        const float* bp = s + box * DIM;
        float obj = bp[4];
        float best = -1.0f; int bidx = sub * 20;
        #pragma unroll
        for (int c = 0; c < 20; ++c) {
            float v = bp[5 + sub * 20 + c] * obj;
            if (v > best) { best = v; bidx = sub * 20 + c; }   // strict > keeps first index
        }
        #pragma unroll
        for (int off = 1; off < 4; off <<= 1) {
            float ob = __shfl_xor(best, off);
            int   oi = __shfl_xor(bidx, off);
            if (ob > best || (ob == best && oi < bidx)) { best = ob; bidx = oi; }
        }
        if (sub == 0) {
            bool m = (obj > 0.25f) && (best > 0.25f);
            float sc = m ? best : -1.0f;
            int gi = b * NP + i0 + box;
            score[gi] = sc;
            clsout[gi] = bidx;
            if (sc > 0.0f) {
                int bin = (int)(__float_as_uint(sc) >> 16) - 0x3E80;
                bin = max(0, min(BINS - 1, bin));
                atomicAdd(&hist[b * BINS + bin], 1);
            }
        }
    }
}

// ---------------------------------------------------------------- gather (+fused threshold)
__global__ __launch_bounds__(1024) void gather_kernel(const float* __restrict__ score,
        const int* __restrict__ hist, int* __restrict__ cnt,
        unsigned long long* __restrict__ keys) {
    int b = blockIdx.x / GBLK;
    int i = (blockIdx.x % GBLK) * 1024 + threadIdx.x;
    __shared__ int h[BINS];
    __shared__ int sT;
    __shared__ int lcnt;
    __shared__ int gbase;
    __shared__ int wbase_s[16];
    if (threadIdx.x < BINS) h[threadIdx.x] = hist[b * BINS + threadIdx.x];
    if (threadIdx.x == 0) lcnt = 0;
    __syncthreads();
    if (threadIdx.x < 64) {
        int lane = threadIdx.x;
        int base = lane * 8;
        int v[8]; int ssum = 0;
        #pragma unroll
        for (int k = 0; k < 8; ++k) { v[k] = h[base + k]; ssum += v[k]; }
        int x = ssum;
        #pragma unroll
        for (int off = 1; off < 64; off <<= 1) {
            int y = __shfl_down(x, off);
            if (lane + off < 64) x += y;
        }
        int run = x - ssum;
        int cand = -1;
        #pragma unroll
        for (int k = 7; k >= 0; --k) {
            run += v[k];
            if (run >= KN && cand < 0) cand = base + k;
        }
        #pragma unroll
        for (int off = 1; off < 64; off <<= 1) cand = max(cand, __shfl_xor(cand, off));
        if (lane == 0) sT = max(cand, 0);
    }
    __syncthreads();
    int T = sT;
    bool want = false;
    float sc = 0.f;
    if (i < NP) {
        sc = score[b * NP + i];
        if (sc > 0.0f) {
            int bin = (int)(__float_as_uint(sc) >> 16) - 0x3E80;
            bin = max(0, min(BINS - 1, bin));
            want = bin >= T;
        }
    }
    unsigned long long mv = __ballot(want);
    int lane = threadIdx.x & 63;
    int wid = threadIdx.x >> 6;
    int nbelow = __popcll(mv & ((1ull << lane) - 1ull));
    if (lane == 0) {
        int wt = (int)__popcll(mv);
        wbase_s[wid] = wt ? atomicAdd(&lcnt, wt) : 0;
    }
    __syncthreads();
    if (threadIdx.x == 0) gbase = lcnt ? atomicAdd(&cnt[b], lcnt) : 0;
    __syncthreads();
    if (want) {
        int pos = gbase + wbase_s[wid] + nbelow;
        if (pos < CAP) {
            unsigned int ii = (unsigned int)i;
            keys[(size_t)b * CAP + pos] =
                ((unsigned long long)__float_as_uint(sc) << 32) | (unsigned int)(~ii);
        }
    }
}

// ---------------------------------------------------------------- sort + build candidates
__global__ __launch_bounds__(1024) void sort_build_kernel(const unsigned long long* __restrict__ keys,
        const int* __restrict__ cnt, const float* __restrict__ preds, const int* __restrict__ cls,
        float4* __restrict__ boxes, float4* __restrict__ boff,
        float* __restrict__ cscore, int* __restrict__ ccls, int* __restrict__ M) {
    int b = blockIdx.x;
    __shared__ unsigned long long k[CAP];
    int n = min(cnt[b], CAP);
    for (int t = threadIdx.x; t < CAP; t += 1024)
        k[t] = (t < n) ? keys[(size_t)b * CAP + t] : 0ull;
    __syncthreads();
    for (int size = 2; size <= CAP; size <<= 1) {
        for (int stride = size >> 1; stride > 0; stride >>= 1) {
            #pragma unroll
            for (int t = threadIdx.x; t < CAP / 2; t += 1024) {
                int i = 2 * t - (t & (stride - 1));
                int j = i + stride;
                bool asc = (t & (size >> 1)) != 0;
                unsigned long long a = k[i], bb = k[j];
                bool sw = asc ? (a > bb) : (a < bb);
                if (sw) { k[i] = bb; k[j] = a; }
            }
            __syncthreads();
        }
    }
    int Mb = min(n, KN);
    for (int r = threadIdx.x; r < KN; r += 1024) {
        float4 bx = make_float4(0.f, 0.f, 0.f, 0.f);
        float4 bo = make_float4(0.f, 0.f, 0.f, 0.f);
        float sc = 0.0f; int c = 0;
        if (r < Mb) {
            unsigned long long key = k[r];
            unsigned int i = ~(unsigned int)key;
            sc = __uint_as_float((unsigned int)(key >> 32));
            const float* p = preds + ((size_t)b * NP + i) * DIM;
            float x = p[0], y = p[1], w = p[2], h = p[3];
            float x1 = x - w * 0.5f, y1 = y - h * 0.5f;
            float x2 = x + w * 0.5f, y2 = y + h * 0.5f;
            c = cls[(size_t)b * NP + i];
            float off = (float)c * 7680.0f;
            bx = make_float4(x1, y1, x2, y2);
            bo = make_float4(x1 + off, y1 + off, x2 + off, y2 + off);
        }
        boxes [b * KN + r] = bx;
        boff  [b * KN + r] = bo;
        cscore[b * KN + r] = sc;
        ccls  [b * KN + r] = c;
    }
    if (threadIdx.x == 0) M[b] = Mb;
}

// ---------------------------------------------------------------- suppression bitmask
__global__ __launch_bounds__(256) void iou_kernel(const float4* __restrict__ boff,
        uint32_t* __restrict__ mask, uint32_t* __restrict__ diag) {
    int b = blockIdx.x >> 5;
    int g = blockIdx.x & 31;           // 64-row group == scan chunk
    __shared__ float4 sb[KN];          // 32 KB
    __shared__ uint32_t mbuf[64 * 64]; // 16 KB
    const float4* Bb = boff + b * KN;
    for (int t = threadIdx.x; t < KN; t += 256) sb[t] = Bb[t];
    __syncthreads();
    int r = threadIdx.x >> 2;
    int w0 = threadIdx.x & 3;
    int i = g * 64 + r;
    float4 bi = sb[i];
    float ai = (bi.z - bi.x) * (bi.w - bi.y);
    #pragma unroll 1
    for (int kk = 0; kk < 16; ++kk) {
        int w = w0 + kk * 4;
        uint32_t bits = 0;
        if (32 * w + 31 > i) {
            #pragma unroll
            for (int jj = 0; jj < 32; ++jj) {
                int j = 32 * w + jj;
                if (j > i) {
                    float4 bj = sb[j];
                    float aj = (bj.z - bj.x) * (bj.w - bj.y);
                    float lx = fmaxf(bi.x, bj.x), ly = fmaxf(bi.y, bj.y);
                    float rx = fminf(bi.z, bj.z), ry = fminf(bi.w, bj.w);
                    float iw = fmaxf(rx - lx, 0.0f), ih = fmaxf(ry - ly, 0.0f);
                    float inter = iw * ih;
                    float iou = inter / (ai + aj - inter + 1e-7f);  // IEEE div, matches np
                    if (iou > 0.45f) bits |= (1u << jj);
                }
            }
        }
        mbuf[r * 64 + w] = bits;
    }
    __syncthreads();
    size_t base = ((size_t)b * KN + (size_t)g * 64) * 64;
    for (int t = threadIdx.x; t < 4096; t += 256) mask[base + t] = mbuf[t];
    if (threadIdx.x < 128) {
        int t = threadIdx.x;
        diag[((size_t)b * 32 + g) * 128 + t] = mbuf[(t >> 1) * 64 + 2 * g + (t & 1)];
    }
}

// ---------------------------------------------------------------- scan (+fused output)
// One wave per batch. Per chunk: issue 64 independent row loads (live only
// within the iteration -> allocatable), run the serial readlane skeep chain
// on resident diag regs (zero memory ops, overlaps load latency), then a
// branchless masked OR where the vmcnt wait lands.
__global__ __launch_bounds__(64, 1) void scan_kernel(const uint32_t* __restrict__ mask,
        const uint32_t* __restrict__ diag, const int* __restrict__ M,
        const float4* __restrict__ boxes, const float* __restrict__ cscore,
        const int* __restrict__ ccls, float* __restrict__ out) {
    int b = blockIdx.x;
    int lane = threadIdx.x;
    const uint32_t* mb = mask + (size_t)b * KN * 64;
    const uint32_t* db = diag + (size_t)b * 32 * 128;
    int Mb = M[b];
    uint32_t sup = 0, keep = 0;
    uint32_t dA = db[lane], dB = db[64 + lane];
    for (int c = 0; c < 32; ++c) {
        // issue the chunk's 64 row-word loads (independent, coalesced)
        uint32_t rowv[64];
        #pragma unroll
        for (int r = 0; r < 64; ++r) rowv[r] = mb[c * 4096 + r * 64 + lane];
        uint32_t ndA = 0, ndB = 0;
        if (c < 31) {
            ndA = db[(c + 1) * 128 + lane];
            ndB = db[(c + 1) * 128 + 64 + lane];
        }
        // serial keep decision — registers only, overlaps in-flight loads
        int base = c * 64;
        uint64_t inval;
        if (Mb <= base) inval = ~0ull;
        else if (Mb >= base + 64) inval = 0ull;
        else inval = ~((1ull << (Mb - base)) - 1ull);
        uint64_t cur64 = inval |
            ((uint64_t)(uint32_t)__builtin_amdgcn_readlane((int)sup, 2 * c + 1) << 32) |
             (uint64_t)(uint32_t)__builtin_amdgcn_readlane((int)sup, 2 * c);
        uint64_t skeep = 0;
        #pragma unroll
        for (int r = 0; r < 64; ++r) {
            if (!((cur64 >> r) & 1ull)) {
                uint32_t lo, hi;
                if (r < 32) {
                    lo = (uint32_t)__builtin_amdgcn_readlane((int)dA, 2 * r);
                    hi = (uint32_t)__builtin_amdgcn_readlane((int)dA, 2 * r + 1);
                } else {
                    lo = (uint32_t)__builtin_amdgcn_readlane((int)dB, 2 * (r - 32));
                    hi = (uint32_t)__builtin_amdgcn_readlane((int)dB, 2 * (r - 32) + 1);
                }
                cur64 |= ((uint64_t)hi << 32) | lo;
                skeep |= 1ull << r;
            }
        }
        // branchless masked OR (vmcnt wait lands here, latency mostly absorbed)
        #pragma unroll
        for (int r = 0; r < 64; ++r) {
            uint32_t mk = (uint32_t)0 - (uint32_t)((skeep >> r) & 1ull);
            sup |= rowv[r] & mk;
        }
        if (lane == 2 * c)     keep |= (uint32_t)skeep;
        if (lane == 2 * c + 1) keep |= (uint32_t)(skeep >> 32);
        dA = ndA; dB = ndB;
    }
    // fused output
    int cnt = __popc(keep);
    int pre = cnt;
    for (int off = 1; off < 64; off <<= 1) {
        int v = __shfl_up(pre, off);
        if (lane >= off) pre += v;
    }
    pre -= cnt;
    uint32_t m = keep;
    while (m) {
        int bit = __ffs(m) - 1;
        m &= m - 1;
        int r = lane * 32 + bit;
        int p = pre++;
        if (p < MAXD) {
            float4 bx = boxes[b * KN + r];
            float* o = out + ((size_t)b * MAXD + p) * 6;
            o[0] = bx.x * 3.0f;      // 1920/640
            o[1] = bx.y * 1.6875f;   // 1080/640
            o[2] = bx.z * 3.0f;
            o[3] = bx.w * 1.6875f;
            o[4] = cscore[b * KN + r];
            o[5] = (float)ccls[b * KN + r];
        }
    }
}

// ---------------------------------------------------------------- launch
extern "C" void kernel_launch(void* const* d_in, const int* in_sizes, int n_in,
                              void* d_out, int out_size, void* d_ws, size_t ws_size,
                              hipStream_t stream) {
    const float* preds = (const float*)d_in[0];
    float* out = (float*)d_out;
    char* ws = (char*)d_ws;
    size_t off = 0;
    auto alloc = [&](size_t bytes) -> void* {
        void* p = ws + off;
        off += (bytes + 255) & ~(size_t)255;
        return p;
    };
    int* hist   = (int*)alloc((size_t)BS * BINS * 4);   // must stay first (memset)
    int* cnt    = (int*)alloc(BS * 4);                  // must stay second (memset)
    float* score = (float*)alloc((size_t)BS * NP * 4);
    int* cls    = (int*)alloc((size_t)BS * NP * 4);
    unsigned long long* keys = (unsigned long long*)alloc((size_t)BS * CAP * 8);
    int* M      = (int*)alloc(BS * 4);
    float4* boxes = (float4*)alloc((size_t)BS * KN * 16);
    float4* boff  = (float4*)alloc((size_t)BS * KN * 16);
    float* cscore = (float*)alloc((size_t)BS * KN * 4);
    int* ccls   = (int*)alloc((size_t)BS * KN * 4);
    uint32_t* mask = (uint32_t*)alloc((size_t)BS * KN * 64 * 4);
    uint32_t* diag = (uint32_t*)alloc((size_t)BS * 32 * 128 * 4);
    if (ws_size < off) return;

    hipMemsetAsync(d_ws, 0, (size_t)BS * BINS * 4 + 256 + 64, stream);  // hist + cnt
    hipMemsetAsync(d_out, 0, (size_t)out_size * 4, stream);

    score_kernel<<<BS * NBLK, 256, 0, stream>>>(preds, score, cls, hist);
    gather_kernel<<<BS * GBLK, 1024, 0, stream>>>(score, hist, cnt, keys);
    sort_build_kernel<<<BS, 1024, 0, stream>>>(keys, cnt, preds, cls, boxes, boff, cscore, ccls, M);
    iou_kernel<<<BS * 32, 256, 0, stream>>>(boff, mask, diag);
    scan_kernel<<<BS, 64, 0, stream>>>(mask, diag, M, boxes, cscore, ccls, out);
}

// Round 9
// 407.791 us; speedup vs baseline: 1.0279x; 1.0279x over previous
//
#include <hip/hip_runtime.h>
#include <stdint.h>

#define BS 16
#define NP 25200
#define NC 80
#define DIM 85
#define KN 2048
#define CAP 4096
#define BINS 512
#define MAXD 300
#define NBLK 394   // ceil(25200/64)
#define GBLK 25    // gather blocks per batch (1024 threads each)

// async global->LDS, 16B per lane (lds dest = wave-uniform base + lane*16)
#define GLOAD_LDS16(g, l) __builtin_amdgcn_global_load_lds( \
    (__attribute__((address_space(1))) void*)(g), \
    (__attribute__((address_space(3))) void*)(l), 16, 0, 0)

// ---------------------------------------------------------------- score
__global__ __launch_bounds__(256) void score_kernel(const float* __restrict__ preds,
        float* __restrict__ score, int* __restrict__ clsout, int* __restrict__ hist) {
    int b = blockIdx.x / NBLK;
    int blk = blockIdx.x % NBLK;
    int i0 = blk * 64;
    int nb = min(64, NP - i0);
    __shared__ float4 s4[64 * DIM / 4];   // 21760 B
    const float4* p4 = (const float4*)(preds + ((size_t)b * NP + i0) * DIM);
    int tot4 = (nb * DIM) >> 2;           // 1360 (full) or 1020 (tail), exact
    int wave = threadIdx.x >> 6, lane = threadIdx.x & 63;
    for (int it = wave; it * 64 < tot4; it += 4) {
        int idx = it * 64 + lane;
        if (idx < tot4) GLOAD_LDS16(p4 + idx, s4 + it * 64);
    }
    __syncthreads();   // compiler drains vmcnt before s_barrier
    const float* s = (const float*)s4;
    int box = threadIdx.x >> 2, sub = threadIdx.x & 3;
    if (box < nb) {
        const float* bp = s + box * DIM;
        float obj = bp[4];
        float best = -1.0f; int bidx = sub * 20;
        #pragma unroll
        for (int c = 0; c < 20; ++c) {
            float v = bp[5 + sub * 20 + c] * obj;
            if (v > best) { best = v; bidx = sub * 20 + c; }   // strict > keeps first index
        }
        #pragma unroll
        for (int off = 1; off < 4; off <<= 1) {
            float ob = __shfl_xor(best, off);
            int   oi = __shfl_xor(bidx, off);
            if (ob > best || (ob == best && oi < bidx)) { best = ob; bidx = oi; }
        }
        if (sub == 0) {
            bool m = (obj > 0.25f) && (best > 0.25f);
            float sc = m ? best : -1.0f;
            int gi = b * NP + i0 + box;
            score[gi] = sc;
            clsout[gi] = bidx;
            if (sc > 0.0f) {
                int bin = (int)(__float_as_uint(sc) >> 16) - 0x3E80;
                bin = max(0, min(BINS - 1, bin));
                atomicAdd(&hist[b * BINS + bin], 1);
            }
        }
    }
}

// ---------------------------------------------------------------- gather (+fused threshold)
__global__ __launch_bounds__(1024) void gather_kernel(const float* __restrict__ score,
        const int* __restrict__ hist, int* __restrict__ cnt,
        unsigned long long* __restrict__ keys) {
    int b = blockIdx.x / GBLK;
    int i = (blockIdx.x % GBLK) * 1024 + threadIdx.x;
    __shared__ int h[BINS];
    __shared__ int sT;
    __shared__ int lcnt;
    __shared__ int gbase;
    __shared__ int wbase_s[16];
    if (threadIdx.x < BINS) h[threadIdx.x] = hist[b * BINS + threadIdx.x];
    if (threadIdx.x == 0) lcnt = 0;
    __syncthreads();
    if (threadIdx.x < 64) {
        int lane = threadIdx.x;
        int base = lane * 8;
        int v[8]; int ssum = 0;
        #pragma unroll
        for (int k = 0; k < 8; ++k) { v[k] = h[base + k]; ssum += v[k]; }
        int x = ssum;
        #pragma unroll
        for (int off = 1; off < 64; off <<= 1) {
            int y = __shfl_down(x, off);
            if (lane + off < 64) x += y;
        }
        int run = x - ssum;
        int cand = -1;
        #pragma unroll
        for (int k = 7; k >= 0; --k) {
            run += v[k];
            if (run >= KN && cand < 0) cand = base + k;
        }
        #pragma unroll
        for (int off = 1; off < 64; off <<= 1) cand = max(cand, __shfl_xor(cand, off));
        if (lane == 0) sT = max(cand, 0);
    }
    __syncthreads();
    int T = sT;
    bool want = false;
    float sc = 0.f;
    if (i < NP) {
        sc = score[b * NP + i];
        if (sc > 0.0f) {
            int bin = (int)(__float_as_uint(sc) >> 16) - 0x3E80;
            bin = max(0, min(BINS - 1, bin));
            want = bin >= T;
        }
    }
    unsigned long long mv = __ballot(want);
    int lane = threadIdx.x & 63;
    int wid = threadIdx.x >> 6;
    int nbelow = __popcll(mv & ((1ull << lane) - 1ull));
    if (lane == 0) {
        int wt = (int)__popcll(mv);
        wbase_s[wid] = wt ? atomicAdd(&lcnt, wt) : 0;
    }
    __syncthreads();
    if (threadIdx.x == 0) gbase = lcnt ? atomicAdd(&cnt[b], lcnt) : 0;
    __syncthreads();
    if (want) {
        int pos = gbase + wbase_s[wid] + nbelow;
        if (pos < CAP) {
            unsigned int ii = (unsigned int)i;
            keys[(size_t)b * CAP + pos] =
                ((unsigned long long)__float_as_uint(sc) << 32) | (unsigned int)(~ii);
        }
    }
}

// ---------------------------------------------------------------- sort + build candidates
__global__ __launch_bounds__(1024) void sort_build_kernel(const unsigned long long* __restrict__ keys,
        const int* __restrict__ cnt, const float* __restrict__ preds, const int* __restrict__ cls,
        float4* __restrict__ boxes, float4* __restrict__ boff,
        float* __restrict__ cscore, int* __restrict__ ccls, int* __restrict__ M) {
    int b = blockIdx.x;
    __shared__ unsigned long long k[CAP];
    int n = min(cnt[b], CAP);
    for (int t = threadIdx.x; t < CAP; t += 1024)
        k[t] = (t < n) ? keys[(size_t)b * CAP + t] : 0ull;
    __syncthreads();
    for (int size = 2; size <= CAP; size <<= 1) {
        for (int stride = size >> 1; stride > 0; stride >>= 1) {
            #pragma unroll
            for (int t = threadIdx.x; t < CAP / 2; t += 1024) {
                int i = 2 * t - (t & (stride - 1));
                int j = i + stride;
                bool asc = (t & (size >> 1)) != 0;
                unsigned long long a = k[i], bb = k[j];
                bool sw = asc ? (a > bb) : (a < bb);
                if (sw) { k[i] = bb; k[j] = a; }
            }
            __syncthreads();
        }
    }
    int Mb = min(n, KN);
    for (int r = threadIdx.x; r < KN; r += 1024) {
        float4 bx = make_float4(0.f, 0.f, 0.f, 0.f);
        float4 bo = make_float4(0.f, 0.f, 0.f, 0.f);
        float sc = 0.0f; int c = 0;
        if (r < Mb) {
            unsigned long long key = k[r];
            unsigned int i = ~(unsigned int)key;
            sc = __uint_as_float((unsigned int)(key >> 32));
            const float* p = preds + ((size_t)b * NP + i) * DIM;
            float x = p[0], y = p[1], w = p[2], h = p[3];
            float x1 = x - w * 0.5f, y1 = y - h * 0.5f;
            float x2 = x + w * 0.5f, y2 = y + h * 0.5f;
            c = cls[(size_t)b * NP + i];
            float off = (float)c * 7680.0f;
            bx = make_float4(x1, y1, x2, y2);
            bo = make_float4(x1 + off, y1 + off, x2 + off, y2 + off);
        }
        boxes [b * KN + r] = bx;
        boff  [b * KN + r] = bo;
        cscore[b * KN + r] = sc;
        ccls  [b * KN + r] = c;
    }
    if (threadIdx.x == 0) M[b] = Mb;
}

// ---------------------------------------------------------------- suppression bitmask
__global__ __launch_bounds__(256) void iou_kernel(const float4* __restrict__ boff,
        uint32_t* __restrict__ mask, uint32_t* __restrict__ diag) {
    int b = blockIdx.x >> 5;
    int g = blockIdx.x & 31;           // 64-row group == scan chunk
    __shared__ float4 sb[KN];          // 32 KB
    __shared__ uint32_t mbuf[64 * 64]; // 16 KB
    const float4* Bb = boff + b * KN;
    for (int t = threadIdx.x; t < KN; t += 256) sb[t] = Bb[t];
    __syncthreads();
    int r = threadIdx.x >> 2;
    int w0 = threadIdx.x & 3;
    int i = g * 64 + r;
    float4 bi = sb[i];
    float ai = (bi.z - bi.x) * (bi.w - bi.y);
    #pragma unroll 1
    for (int kk = 0; kk < 16; ++kk) {
        int w = w0 + kk * 4;
        uint32_t bits = 0;
        if (32 * w + 31 > i) {
            #pragma unroll
            for (int jj = 0; jj < 32; ++jj) {
                int j = 32 * w + jj;
                if (j > i) {
                    float4 bj = sb[j];
                    float aj = (bj.z - bj.x) * (bj.w - bj.y);
                    float lx = fmaxf(bi.x, bj.x), ly = fmaxf(bi.y, bj.y);
                    float rx = fminf(bi.z, bj.z), ry = fminf(bi.w, bj.w);
                    float iw = fmaxf(rx - lx, 0.0f), ih = fmaxf(ry - ly, 0.0f);
                    float inter = iw * ih;
                    float iou = inter / (ai + aj - inter + 1e-7f);  // IEEE div, matches np
                    if (iou > 0.45f) bits |= (1u << jj);
                }
            }
        }
        mbuf[r * 64 + w] = bits;
    }
    __syncthreads();
    size_t base = ((size_t)b * KN + (size_t)g * 64) * 64;
    for (int t = threadIdx.x; t < 4096; t += 256) mask[base + t] = mbuf[t];
    if (threadIdx.x < 128) {
        int t = threadIdx.x;
        diag[((size_t)b * 32 + g) * 128 + t] = mbuf[(t >> 1) * 64 + 2 * g + (t & 1)];
    }
}

// ---------------------------------------------------------------- scan (+fused output)
// 1024 threads/batch. Per chunk: ALL waves issue 4 coalesced row loads
// (4 live regs/thread — nothing for the allocator to dismantle; 16 waves of
// TLP hide latency), wave 0 runs the serial readlane chain concurrently and
// publishes skeep via LDS; after a barrier every thread masked-ORs its 4 rows
// into a 64-word LDS sup array (atomicOr skipped when contribution is 0).
__global__ __launch_bounds__(1024) void scan_kernel(const uint32_t* __restrict__ mask,
        const uint32_t* __restrict__ diag, const int* __restrict__ M,
        const float4* __restrict__ boxes, const float* __restrict__ cscore,
        const int* __restrict__ ccls, float* __restrict__ out) {
    int b = blockIdx.x;
    int tid = threadIdx.x;
    int lane = tid & 63;
    const uint32_t* mb = mask + (size_t)b * KN * 64;
    const uint32_t* db = diag + (size_t)b * 32 * 128;
    int Mb = M[b];
    __shared__ uint32_t supLDS[64];
    __shared__ uint32_t skeepLDS[2];
    if (tid < 64) supLDS[tid] = 0u;
    __syncthreads();
    int rbase = (tid >> 6) * 4;   // this thread's 4 rows within the chunk
    uint32_t keep = 0;            // wave 0 only
    uint32_t dA = 0, dB = 0;
    if (tid < 64) { dA = db[lane]; dB = db[64 + lane]; }
    for (int c = 0; c < 32; ++c) {
        // issue this chunk's row loads (independent of skeep)
        const uint32_t* cb = mb + c * 4096;
        uint32_t r0 = cb[(rbase + 0) * 64 + lane];
        uint32_t r1 = cb[(rbase + 1) * 64 + lane];
        uint32_t r2 = cb[(rbase + 2) * 64 + lane];
        uint32_t r3 = cb[(rbase + 3) * 64 + lane];
        if (tid < 64) {
            uint32_t ndA = 0, ndB = 0;
            if (c < 31) {           // prefetch next chunk's diag
                ndA = db[(c + 1) * 128 + lane];
                ndB = db[(c + 1) * 128 + 64 + lane];
            }
            int base = c * 64;
            uint64_t inval;
            if (Mb <= base) inval = ~0ull;
            else if (Mb >= base + 64) inval = 0ull;
            else inval = ~((1ull << (Mb - base)) - 1ull);
            uint64_t cur64 = inval |
                ((uint64_t)supLDS[2 * c + 1] << 32) | (uint64_t)supLDS[2 * c];
            uint64_t skeep = 0;
            #pragma unroll
            for (int r = 0; r < 64; ++r) {
                if (!((cur64 >> r) & 1ull)) {
                    uint32_t lo, hi;
                    if (r < 32) {
                        lo = (uint32_t)__builtin_amdgcn_readlane((int)dA, 2 * r);
                        hi = (uint32_t)__builtin_amdgcn_readlane((int)dA, 2 * r + 1);
                    } else {
                        lo = (uint32_t)__builtin_amdgcn_readlane((int)dB, 2 * (r - 32));
                        hi = (uint32_t)__builtin_amdgcn_readlane((int)dB, 2 * (r - 32) + 1);
                    }
                    cur64 |= ((uint64_t)hi << 32) | lo;
                    skeep |= 1ull << r;
                }
            }
            if (tid == 0) {
                skeepLDS[0] = (uint32_t)skeep;
                skeepLDS[1] = (uint32_t)(skeep >> 32);
            }
            if (lane == 2 * c)     keep |= (uint32_t)skeep;
            if (lane == 2 * c + 1) keep |= (uint32_t)(skeep >> 32);
            dA = ndA; dB = ndB;
        }
        __syncthreads();   // skeep published; row loads drained
        uint64_t sk = ((uint64_t)skeepLDS[1] << 32) | (uint64_t)skeepLDS[0];
        uint32_t orv = (r0 & (uint32_t)(0u - (uint32_t)((sk >> (rbase + 0)) & 1ull)))
                     | (r1 & (uint32_t)(0u - (uint32_t)((sk >> (rbase + 1)) & 1ull)))
                     | (r2 & (uint32_t)(0u - (uint32_t)((sk >> (rbase + 2)) & 1ull)))
                     | (r3 & (uint32_t)(0u - (uint32_t)((sk >> (rbase + 3)) & 1ull)));
        if (orv) atomicOr(&supLDS[lane], orv);
        __syncthreads();   // sup updated before wave 0 reads it next chunk
    }
    // fused output (wave 0)
    if (tid < 64) {
        int cnt = __popc(keep);
        int pre = cnt;
        for (int off = 1; off < 64; off <<= 1) {
            int v = __shfl_up(pre, off);
            if (lane >= off) pre += v;
        }
        pre -= cnt;
        uint32_t m = keep;
        while (m) {
            int bit = __ffs(m) - 1;
            m &= m - 1;
            int r = lane * 32 + bit;
            int p = pre++;
            if (p < MAXD) {
                float4 bx = boxes[b * KN + r];
                float* o = out + ((size_t)b * MAXD + p) * 6;
                o[0] = bx.x * 3.0f;      // 1920/640
                o[1] = bx.y * 1.6875f;   // 1080/640
                o[2] = bx.z * 3.0f;
                o[3] = bx.w * 1.6875f;
                o[4] = cscore[b * KN + r];
                o[5] = (float)ccls[b * KN + r];
            }
        }
    }
}

// ---------------------------------------------------------------- launch
extern "C" void kernel_launch(void* const* d_in, const int* in_sizes, int n_in,
                              void* d_out, int out_size, void* d_ws, size_t ws_size,
                              hipStream_t stream) {
    const float* preds = (const float*)d_in[0];
    float* out = (float*)d_out;
    char* ws = (char*)d_ws;
    size_t off = 0;
    auto alloc = [&](size_t bytes) -> void* {
        void* p = ws + off;
        off += (bytes + 255) & ~(size_t)255;
        return p;
    };
    int* hist   = (int*)alloc((size_t)BS * BINS * 4);   // must stay first (memset)
    int* cnt    = (int*)alloc(BS * 4);                  // must stay second (memset)
    float* score = (float*)alloc((size_t)BS * NP * 4);
    int* cls    = (int*)alloc((size_t)BS * NP * 4);
    unsigned long long* keys = (unsigned long long*)alloc((size_t)BS * CAP * 8);
    int* M      = (int*)alloc(BS * 4);
    float4* boxes = (float4*)alloc((size_t)BS * KN * 16);
    float4* boff  = (float4*)alloc((size_t)BS * KN * 16);
    float* cscore = (float*)alloc((size_t)BS * KN * 4);
    int* ccls   = (int*)alloc((size_t)BS * KN * 4);
    uint32_t* mask = (uint32_t*)alloc((size_t)BS * KN * 64 * 4);
    uint32_t* diag = (uint32_t*)alloc((size_t)BS * 32 * 128 * 4);
    if (ws_size < off) return;

    hipMemsetAsync(d_ws, 0, (size_t)BS * BINS * 4 + 256 + 64, stream);  // hist + cnt
    hipMemsetAsync(d_out, 0, (size_t)out_size * 4, stream);

    score_kernel<<<BS * NBLK, 256, 0, stream>>>(preds, score, cls, hist);
    gather_kernel<<<BS * GBLK, 1024, 0, stream>>>(score, hist, cnt, keys);
    sort_build_kernel<<<BS, 1024, 0, stream>>>(keys, cnt, preds, cls, boxes, boff, cscore, ccls, M);
    iou_kernel<<<BS * 32, 256, 0, stream>>>(boff, mask, diag);
    scan_kernel<<<BS, 1024, 0, stream>>>(mask, diag, M, boxes, cscore, ccls, out);
}